// Round 10
// baseline (397.482 us; speedup 1.0000x reference)
//
#include <hip/hip_runtime.h>
#include <hip/hip_bf16.h>

#define BDIM 8192
#define DDIM 256

typedef __attribute__((ext_vector_type(8))) short  s16x8;   // 8 x bf16 (4 VGPRs)
typedef __attribute__((ext_vector_type(4))) float  f32x4;   // MFMA accumulator
typedef __attribute__((ext_vector_type(4))) float  fv4;     // clang float4

__device__ inline ushort f2bf(float x) {
    __hip_bfloat16 h = __float2bfloat16(x);
    ushort u;
    __builtin_memcpy(&u, &h, 2);
    return u;
}

// ---------------------------------------------------------------------------
// Kernel A: per-row stats + fragment-swizzled bf16 a_hat (layout-1).
//   u16 index(row,d) = (row>>4)*4096 + (d>>5)*512 + ((d>>3)&3)*128
//                      + (row&15)*8 + (d&7)      (verified: absmax 0.0)
// ---------------------------------------------------------------------------
__global__ __launch_bounds__(256) void row_stats(
    const float* __restrict__ A, const float* __restrict__ P,
    const float* __restrict__ N, ushort* __restrict__ Asw,
    float* __restrict__ partial_trip)
{
    __shared__ float tsh[4];
    const int wave = threadIdx.x >> 6;
    const int lane = threadIdx.x & 63;
    const int row  = blockIdx.x * 4 + wave;

    const float4 a = *(reinterpret_cast<const float4*>(A + (size_t)row * DDIM) + lane);
    const float4 p = *(reinterpret_cast<const float4*>(P + (size_t)row * DDIM) + lane);
    const float4 n = *(reinterpret_cast<const float4*>(N + (size_t)row * DDIM) + lane);

    float sa = a.x*a.x + a.y*a.y + a.z*a.z + a.w*a.w;

    float d0 = a.x - p.x + 1e-6f, d1 = a.y - p.y + 1e-6f;
    float d2 = a.z - p.z + 1e-6f, d3 = a.w - p.w + 1e-6f;
    float sp = d0*d0 + d1*d1 + d2*d2 + d3*d3;

    d0 = a.x - n.x + 1e-6f; d1 = a.y - n.y + 1e-6f;
    d2 = a.z - n.z + 1e-6f; d3 = a.w - n.w + 1e-6f;
    float sn = d0*d0 + d1*d1 + d2*d2 + d3*d3;

    #pragma unroll
    for (int off = 32; off > 0; off >>= 1) {
        sa += __shfl_xor(sa, off);
        sp += __shfl_xor(sp, off);
        sn += __shfl_xor(sn, off);
    }

    const float inv = 1.0f / fmaxf(sqrtf(sa), 1e-8f);

    ushort4 hv;
    hv.x = f2bf(a.x * inv);
    hv.y = f2bf(a.y * inv);
    hv.z = f2bf(a.z * inv);
    hv.w = f2bf(a.w * inv);
    const size_t chunk = ((size_t)(row >> 4) * 8 + (lane >> 3)) * 64
                       + (size_t)(((lane >> 1) & 3) * 16 + (row & 15));
    *reinterpret_cast<ushort4*>(Asw + chunk * 8 + (lane & 1) * 4) = hv;

    if (lane == 0)
        tsh[wave] = fmaxf(sqrtf(sp) - sqrtf(sn) + 0.2f, 0.0f);
    __syncthreads();
    if (threadIdx.x == 0)
        partial_trip[blockIdx.x] = tsh[0] + tsh[1] + tsh[2] + tsh[3];
}

// ---------------------------------------------------------------------------
// Kernel T: layout-2 (A_hat^T fragment chunks) from layout-1.
//   u16 base((d0>>4),(j0>>5)) = ((d0>>4)*256 + (j0>>5))*512; lane l holds
//   A_hat[j0 + (l>>4)*8 + jj][d0 + (l&15)], jj=0..7 -> 1KB coalesced frag.
// ---------------------------------------------------------------------------
__global__ __launch_bounds__(256) void transpose_ahat(
    const ushort* __restrict__ Asw, ushort* __restrict__ Asw2)
{
    const int t = threadIdx.x, w = t >> 6, lane = t & 63;
    const int fr = lane & 15, kg = lane >> 4;
    const int b = blockIdx.x;                 // 64 blocks
    const int j0 = b * 128 + w * 32;

    #pragma unroll 1
    for (int D = 0; D < 16; ++D) {
        const int d = D * 16 + fr;
        ushort v[8];
        #pragma unroll
        for (int jj = 0; jj < 8; ++jj) {
            const int J = j0 + kg * 8 + jj;
            v[jj] = Asw[(size_t)(J >> 4) * 4096 + (d >> 5) * 512
                        + ((d >> 3) & 3) * 128 + (J & 15) * 8 + (d & 7)];
        }
        uint4 pk;
        pk.x = v[0] | ((unsigned)v[1] << 16);
        pk.y = v[2] | ((unsigned)v[3] << 16);
        pk.z = v[4] | ((unsigned)v[5] << 16);
        pk.w = v[6] | ((unsigned)v[7] << 16);
        *reinterpret_cast<uint4*>(
            Asw2 + (size_t)(D * 256 + b * 4 + w) * 512 + (size_t)lane * 8) = pk;
    }
}

// ---------------------------------------------------------------------------
// Kernel G: Gram partials  M = A_hat^T A_hat (256x256), K split in 32 chunks.
// ---------------------------------------------------------------------------
__global__ __launch_bounds__(256, 2) void gram(
    const ushort* __restrict__ Asw2, float* __restrict__ Mpart)
{
    const int t = threadIdx.x, w = t >> 6, lane = t & 63;
    const int fr = lane & 15, kg = lane >> 4;
    const int kc = blockIdx.x;   // 0..31
    const int h  = blockIdx.y;   // 0..1

    f32x4 acc[8][4] = {};
    #pragma unroll 1
    for (int k32 = 0; k32 < 8; ++k32) {
        const int j5 = (kc * 256 + k32 * 32) >> 5;
        s16x8 af[8], bf[4];
        #pragma unroll
        for (int m = 0; m < 8; ++m)
            af[m] = *reinterpret_cast<const s16x8*>(
                Asw2 + ((size_t)((h * 8 + m) * 256 + j5)) * 512 + lane * 8);
        #pragma unroll
        for (int n = 0; n < 4; ++n)
            bf[n] = *reinterpret_cast<const s16x8*>(
                Asw2 + ((size_t)((w * 4 + n) * 256 + j5)) * 512 + lane * 8);
        #pragma unroll
        for (int m = 0; m < 8; ++m)
            #pragma unroll
            for (int n = 0; n < 4; ++n)
                acc[m][n] = __builtin_amdgcn_mfma_f32_16x16x32_bf16(
                    af[m], bf[n], acc[m][n], 0, 0, 0);
    }
    float* base = Mpart + (size_t)kc * 65536
                + (size_t)(h * 128 + kg * 4) * 256 + w * 64 + fr;
    #pragma unroll
    for (int m = 0; m < 8; ++m)
        #pragma unroll
        for (int reg = 0; reg < 4; ++reg)
            #pragma unroll
            for (int n = 0; n < 4; ++n)
                base[(size_t)(m * 16 + reg) * 256 + n * 16] = acc[m][n][reg];
}

__global__ __launch_bounds__(256) void gram_reduce(
    const float* __restrict__ Mpart, float* __restrict__ gpart)
{
    __shared__ float sh[4];
    const int t = threadIdx.x;
    const int id = blockIdx.x * 256 + t;
    float ss = 0.f;
    for (int e = id; e < 65536; e += 16384) {
        float s = 0.f;
        #pragma unroll 4
        for (int kc = 0; kc < 32; ++kc)
            s += Mpart[(size_t)kc * 65536 + e];
        ss += s * s;
    }
    #pragma unroll
    for (int off = 32; off > 0; off >>= 1) ss += __shfl_down(ss, off);
    const int w = t >> 6, lane = t & 63;
    if (lane == 0) sh[w] = ss;
    __syncthreads();
    if (t == 0) gpart[blockIdx.x] = sh[0] + sh[1] + sh[2] + sh[3];
}

// ---------------------------------------------------------------------------
// Kernel D (LDS-broadcast): trace(A_hat^T S A_hat) partials + sum(S^2).
// 2048 blocks x 512 thr (8 waves). Block owns (i-group 256 rows, k-chunk
// 128 cols). The block's ENTIRE A_hat^T fragment slice (16 d-tiles x 4 k32
// x 1KB = 64 KB) is staged to LDS ONCE (single barrier) -> fragment reads
// become ds_read (lgkmcnt) and NEVER interlock with the S stream (vmcnt).
// Each wave then free-runs a 32-row strip: per k32, load S 32x32 f32
// (4 fv4/lane, 1-deep prefetch), cvt to two A-frags, 16 ds_read frags,
// 32 MFMA. bf L2 traffic: was 2 GB (R9) -> 128 MB; LDS serves 1 GB @69TB/s.
// Epilogue: dot(acc, A_hat layout-1) per sub-strip (R9-verified mapping).
// ---------------------------------------------------------------------------
__global__ __launch_bounds__(512) void s_dot(
    const float* __restrict__ S, const ushort* __restrict__ Asw,
    const ushort* __restrict__ Asw2,
    float* __restrict__ dotp, float* __restrict__ s2p)
{
    __shared__ ushort frg[64 * 512];   // 64 KB: chunk (dt*4+k32) -> 512 u16

    const int t = threadIdx.x;          // 0..511
    const int w = t >> 6, lane = t & 63;
    const int fr = lane & 15, kg = lane >> 4;

    const int bid = blockIdx.x;         // 0..2047
    const int kc  = bid & 63;           // k-chunk: cols [kc*128, +128)
    const int ig  = bid >> 6;           // i-group: rows [ig*256, +256)
    const int i0  = ig * 256 + w * 32;  // wave's 32-row strip

    // ---- stage the fragment slice (4096 uint4, coalesced 1KB per 64 thr)
    {
        const int kc4 = kc * 4;
        #pragma unroll
        for (int j = 0; j < 8; ++j) {
            const int idx   = j * 512 + t;     // 0..4095
            const int chunk = idx >> 6;        // dt*4 + k32
            const int off   = idx & 63;
            const int dt    = chunk >> 2, k32 = chunk & 3;
            *reinterpret_cast<uint4*>(&frg[chunk * 512 + off * 8]) =
                *reinterpret_cast<const uint4*>(
                    Asw2 + (size_t)(dt * 256 + kc4 + k32) * 512 + off * 8);
        }
    }
    __syncthreads();

    // lane's S rows: sub0 = i0+fr, sub1 = i0+16+fr; cols kc*128 + k32*32 + kg*8
    const float* sg0 = S + (size_t)(i0 + fr) * BDIM + kc * 128 + kg * 8;
    const float* sg1 = sg0 + (size_t)16 * BDIM;

    f32x4 acc0[16] = {};
    f32x4 acc1[16] = {};
    float s2 = 0.f;

    fv4 u0 = *reinterpret_cast<const fv4*>(sg0);
    fv4 v0 = *reinterpret_cast<const fv4*>(sg0 + 4);
    fv4 u1 = *reinterpret_cast<const fv4*>(sg1);
    fv4 v1 = *reinterpret_cast<const fv4*>(sg1 + 4);

    #pragma unroll 1
    for (int k = 0; k < 4; ++k) {
        fv4 nu0, nv0, nu1, nv1;
        if (k < 3) {
            const float* p0 = sg0 + (size_t)(k + 1) * 32;
            const float* p1 = sg1 + (size_t)(k + 1) * 32;
            nu0 = *reinterpret_cast<const fv4*>(p0);
            nv0 = *reinterpret_cast<const fv4*>(p0 + 4);
            nu1 = *reinterpret_cast<const fv4*>(p1);
            nv1 = *reinterpret_cast<const fv4*>(p1 + 4);
        }

        s16x8 af0, af1;
        af0[0] = (short)f2bf(u0.x); af0[1] = (short)f2bf(u0.y);
        af0[2] = (short)f2bf(u0.z); af0[3] = (short)f2bf(u0.w);
        af0[4] = (short)f2bf(v0.x); af0[5] = (short)f2bf(v0.y);
        af0[6] = (short)f2bf(v0.z); af0[7] = (short)f2bf(v0.w);
        af1[0] = (short)f2bf(u1.x); af1[1] = (short)f2bf(u1.y);
        af1[2] = (short)f2bf(u1.z); af1[3] = (short)f2bf(u1.w);
        af1[4] = (short)f2bf(v1.x); af1[5] = (short)f2bf(v1.y);
        af1[6] = (short)f2bf(v1.z); af1[7] = (short)f2bf(v1.w);
        s2 += u0.x*u0.x + u0.y*u0.y + u0.z*u0.z + u0.w*u0.w
            + v0.x*v0.x + v0.y*v0.y + v0.z*v0.z + v0.w*v0.w
            + u1.x*u1.x + u1.y*u1.y + u1.z*u1.z + u1.w*u1.w
            + v1.x*v1.x + v1.y*v1.y + v1.z*v1.z + v1.w*v1.w;

        const ushort* fb = frg + (size_t)k * 512 + lane * 8;
        #pragma unroll
        for (int dt = 0; dt < 16; ++dt) {
            const s16x8 bf = *reinterpret_cast<const s16x8*>(fb + dt * 2048);
            acc0[dt] = __builtin_amdgcn_mfma_f32_16x16x32_bf16(af0, bf, acc0[dt], 0, 0, 0);
            acc1[dt] = __builtin_amdgcn_mfma_f32_16x16x32_bf16(af1, bf, acc1[dt], 0, 0, 0);
        }

        u0 = nu0; v0 = nv0; u1 = nu1; v1 = nv1;
    }

    // ---- epilogue: dot(acc, A_hat); C layout col=fr -> d, row=kg*4+reg
    float dot = 0.f;
    #pragma unroll 1
    for (int dt = 0; dt < 16; ++dt) {
        const int d = dt * 16 + fr;
        const size_t ab0 = (size_t)(i0 >> 4) * 4096 + (size_t)(d >> 5) * 512
                         + (size_t)((d >> 3) & 3) * 128 + (size_t)(kg * 32) + (d & 7);
        #pragma unroll
        for (int reg = 0; reg < 4; ++reg) {
            const ushort uu = Asw[ab0 + reg * 8];
            dot += __uint_as_float((unsigned)uu << 16) * acc0[dt][reg];
        }
        #pragma unroll
        for (int reg = 0; reg < 4; ++reg) {
            const ushort uu = Asw[ab0 + 4096 + reg * 8];
            dot += __uint_as_float((unsigned)uu << 16) * acc1[dt][reg];
        }
    }

    #pragma unroll
    for (int off = 32; off > 0; off >>= 1) {
        dot += __shfl_down(dot, off);
        s2  += __shfl_down(s2, off);
    }
    if (lane == 0) {
        dotp[bid * 8 + w] = dot;
        s2p[bid * 8 + w]  = s2;
    }
}

// ---------------------------------------------------------------------------
// finalize: out = trip/B + (gram_ss - 2*dot + s2) / B^2
// ---------------------------------------------------------------------------
__global__ __launch_bounds__(256) void finalize(
    const float* __restrict__ pt, const float* __restrict__ dotp,
    const float* __restrict__ s2p, const float* __restrict__ gpart,
    float* __restrict__ out)
{
    __shared__ float sh[4];
    const int t = threadIdx.x;
    float trip = 0.f, sim = 0.f;
    for (int i = t; i < 2048; i += 256) trip += pt[i];
    for (int i = t; i < 16384; i += 256) sim += -2.f * dotp[i] + s2p[i];
    if (t < 64) sim += gpart[t];
    float v = trip * (1.0f / (float)BDIM)
            + sim  * (1.0f / ((float)BDIM * (float)BDIM));
    #pragma unroll
    for (int off = 32; off > 0; off >>= 1) v += __shfl_down(v, off);
    const int w = t >> 6, lane = t & 63;
    if (lane == 0) sh[w] = v;
    __syncthreads();
    if (t == 0) out[0] = sh[0] + sh[1] + sh[2] + sh[3];
}

extern "C" void kernel_launch(void* const* d_in, const int* in_sizes, int n_in,
                              void* d_out, int out_size, void* d_ws, size_t ws_size,
                              hipStream_t stream)
{
    const float* anchor   = (const float*)d_in[0];
    const float* positive = (const float*)d_in[1];
    const float* negative = (const float*)d_in[2];
    const float* S        = (const float*)d_in[3];
    float* out = (float*)d_out;

    float*  pt    = (float*)d_ws;                          // 2048 f
    float*  gpart = (float*)((char*)d_ws + 16384);         // 64 f
    float*  dotp  = (float*)((char*)d_ws + 65536);         // 16384 f
    float*  s2p   = (float*)((char*)d_ws + 131072);        // 16384 f
    ushort* Asw   = (ushort*)((char*)d_ws + (1u  << 20));  // 4 MB layout-1
    ushort* Asw2  = (ushort*)((char*)d_ws + (8u  << 20));  // 4 MB layout-2
    float*  Mpart = (float*)((char*)d_ws + (16u << 20));   // 8 MB gram partials

    row_stats<<<BDIM / 4, 256, 0, stream>>>(anchor, positive, negative, Asw, pt);
    transpose_ahat<<<64, 256, 0, stream>>>(Asw, Asw2);
    gram<<<dim3(32, 2), 256, 0, stream>>>(Asw2, Mpart);
    gram_reduce<<<64, 256, 0, stream>>>(Mpart, gpart);
    s_dot<<<2048, 512, 0, stream>>>(S, Asw, Asw2, dotp, s2p);
    finalize<<<1, 256, 0, stream>>>(pt, dotp, s2p, gpart, out);
}

// Round 11
// 147.589 us; speedup vs baseline: 2.6932x; 2.6932x over previous
//
#include <hip/hip_runtime.h>
#include <hip/hip_bf16.h>

#define BDIM 8192
#define DDIM 256

typedef __attribute__((ext_vector_type(8))) short  s16x8;   // 8 x bf16 (4 VGPRs)
typedef __attribute__((ext_vector_type(4))) float  f32x4;   // MFMA accumulator
typedef __attribute__((ext_vector_type(4))) float  fv4;     // clang float4

#define REP16(M) M(0) M(1) M(2) M(3) M(4) M(5) M(6) M(7) \
                 M(8) M(9) M(10) M(11) M(12) M(13) M(14) M(15)

__device__ inline ushort f2bf(float x) {
    __hip_bfloat16 h = __float2bfloat16(x);
    ushort u;
    __builtin_memcpy(&u, &h, 2);
    return u;
}

// ---------------------------------------------------------------------------
// Kernel A: per-row stats + fragment-swizzled bf16 a_hat (layout-1).
//   u16 index(row,d) = (row>>4)*4096 + (d>>5)*512 + ((d>>3)&3)*128
//                      + (row&15)*8 + (d&7)      (verified: absmax 0.0)
// ---------------------------------------------------------------------------
__global__ __launch_bounds__(256) void row_stats(
    const float* __restrict__ A, const float* __restrict__ P,
    const float* __restrict__ N, ushort* __restrict__ Asw,
    float* __restrict__ partial_trip)
{
    __shared__ float tsh[4];
    const int wave = threadIdx.x >> 6;
    const int lane = threadIdx.x & 63;
    const int row  = blockIdx.x * 4 + wave;

    const float4 a = *(reinterpret_cast<const float4*>(A + (size_t)row * DDIM) + lane);
    const float4 p = *(reinterpret_cast<const float4*>(P + (size_t)row * DDIM) + lane);
    const float4 n = *(reinterpret_cast<const float4*>(N + (size_t)row * DDIM) + lane);

    float sa = a.x*a.x + a.y*a.y + a.z*a.z + a.w*a.w;

    float d0 = a.x - p.x + 1e-6f, d1 = a.y - p.y + 1e-6f;
    float d2 = a.z - p.z + 1e-6f, d3 = a.w - p.w + 1e-6f;
    float sp = d0*d0 + d1*d1 + d2*d2 + d3*d3;

    d0 = a.x - n.x + 1e-6f; d1 = a.y - n.y + 1e-6f;
    d2 = a.z - n.z + 1e-6f; d3 = a.w - n.w + 1e-6f;
    float sn = d0*d0 + d1*d1 + d2*d2 + d3*d3;

    #pragma unroll
    for (int off = 32; off > 0; off >>= 1) {
        sa += __shfl_xor(sa, off);
        sp += __shfl_xor(sp, off);
        sn += __shfl_xor(sn, off);
    }

    const float inv = 1.0f / fmaxf(sqrtf(sa), 1e-8f);

    ushort4 hv;
    hv.x = f2bf(a.x * inv);
    hv.y = f2bf(a.y * inv);
    hv.z = f2bf(a.z * inv);
    hv.w = f2bf(a.w * inv);
    const size_t chunk = ((size_t)(row >> 4) * 8 + (lane >> 3)) * 64
                       + (size_t)(((lane >> 1) & 3) * 16 + (row & 15));
    *reinterpret_cast<ushort4*>(Asw + chunk * 8 + (lane & 1) * 4) = hv;

    if (lane == 0)
        tsh[wave] = fmaxf(sqrtf(sp) - sqrtf(sn) + 0.2f, 0.0f);
    __syncthreads();
    if (threadIdx.x == 0)
        partial_trip[blockIdx.x] = tsh[0] + tsh[1] + tsh[2] + tsh[3];
}

// ---------------------------------------------------------------------------
// Kernel T: layout-2 (A_hat^T fragment chunks) from layout-1.
// ---------------------------------------------------------------------------
__global__ __launch_bounds__(256) void transpose_ahat(
    const ushort* __restrict__ Asw, ushort* __restrict__ Asw2)
{
    const int t = threadIdx.x, w = t >> 6, lane = t & 63;
    const int fr = lane & 15, kg = lane >> 4;
    const int b = blockIdx.x;                 // 64 blocks
    const int j0 = b * 128 + w * 32;

    #pragma unroll 1
    for (int D = 0; D < 16; ++D) {
        const int d = D * 16 + fr;
        ushort v[8];
        #pragma unroll
        for (int jj = 0; jj < 8; ++jj) {
            const int J = j0 + kg * 8 + jj;
            v[jj] = Asw[(size_t)(J >> 4) * 4096 + (d >> 5) * 512
                        + ((d >> 3) & 3) * 128 + (J & 15) * 8 + (d & 7)];
        }
        uint4 pk;
        pk.x = v[0] | ((unsigned)v[1] << 16);
        pk.y = v[2] | ((unsigned)v[3] << 16);
        pk.z = v[4] | ((unsigned)v[5] << 16);
        pk.w = v[6] | ((unsigned)v[7] << 16);
        *reinterpret_cast<uint4*>(
            Asw2 + (size_t)(D * 256 + b * 4 + w) * 512 + (size_t)lane * 8) = pk;
    }
}

// ---------------------------------------------------------------------------
// Kernel G: Gram partials  M = A_hat^T A_hat (256x256), K split in 32 chunks.
// ---------------------------------------------------------------------------
__global__ __launch_bounds__(256, 2) void gram(
    const ushort* __restrict__ Asw2, float* __restrict__ Mpart)
{
    const int t = threadIdx.x, w = t >> 6, lane = t & 63;
    const int fr = lane & 15, kg = lane >> 4;
    const int kc = blockIdx.x;   // 0..31
    const int h  = blockIdx.y;   // 0..1

    f32x4 acc[8][4] = {};
    #pragma unroll 1
    for (int k32 = 0; k32 < 8; ++k32) {
        const int j5 = (kc * 256 + k32 * 32) >> 5;
        s16x8 af[8], bf[4];
        #pragma unroll
        for (int m = 0; m < 8; ++m)
            af[m] = *reinterpret_cast<const s16x8*>(
                Asw2 + ((size_t)((h * 8 + m) * 256 + j5)) * 512 + lane * 8);
        #pragma unroll
        for (int n = 0; n < 4; ++n)
            bf[n] = *reinterpret_cast<const s16x8*>(
                Asw2 + ((size_t)((w * 4 + n) * 256 + j5)) * 512 + lane * 8);
        #pragma unroll
        for (int m = 0; m < 8; ++m)
            #pragma unroll
            for (int n = 0; n < 4; ++n)
                acc[m][n] = __builtin_amdgcn_mfma_f32_16x16x32_bf16(
                    af[m], bf[n], acc[m][n], 0, 0, 0);
    }
    float* base = Mpart + (size_t)kc * 65536
                + (size_t)(h * 128 + kg * 4) * 256 + w * 64 + fr;
    #pragma unroll
    for (int m = 0; m < 8; ++m)
        #pragma unroll
        for (int reg = 0; reg < 4; ++reg)
            #pragma unroll
            for (int n = 0; n < 4; ++n)
                base[(size_t)(m * 16 + reg) * 256 + n * 16] = acc[m][n][reg];
}

__global__ __launch_bounds__(256) void gram_reduce(
    const float* __restrict__ Mpart, float* __restrict__ gpart)
{
    __shared__ float sh[4];
    const int t = threadIdx.x;
    const int id = blockIdx.x * 256 + t;
    float ss = 0.f;
    for (int e = id; e < 65536; e += 16384) {
        float s = 0.f;
        #pragma unroll 4
        for (int kc = 0; kc < 32; ++kc)
            s += Mpart[(size_t)kc * 65536 + e];
        ss += s * s;
    }
    #pragma unroll
    for (int off = 32; off > 0; off >>= 1) ss += __shfl_down(ss, off);
    const int w = t >> 6, lane = t & 63;
    if (lane == 0) sh[w] = ss;
    __syncthreads();
    if (t == 0) gpart[blockIdx.x] = sh[0] + sh[1] + sh[2] + sh[3];
}

// ---------------------------------------------------------------------------
// Kernel D (LDS-broadcast, spill-free): trace(A_hat^T S A_hat) + sum(S^2).
// Same structure as R10 (which had the right traffic shape) with the ONE
// fix: the epilogue dt-loop is now FULLY UNROLLED so every acc access is
// compile-time-indexed -> accumulators stay in VGPRs (R10: runtime-indexed
// epilogue put acc[] in scratch -> 1.07 GB HBM writes, VGPR_Count 96).
// S loads are nontemporal (zero-reuse stream; keeps Asw2/Asw L2-resident).
// ---------------------------------------------------------------------------
__global__ __launch_bounds__(512) void s_dot(
    const float* __restrict__ S, const ushort* __restrict__ Asw,
    const ushort* __restrict__ Asw2,
    float* __restrict__ dotp, float* __restrict__ s2p)
{
    __shared__ ushort frg[64 * 512];   // 64 KB: chunk (dt*4+k32) -> 512 u16

    const int t = threadIdx.x;          // 0..511
    const int w = t >> 6, lane = t & 63;
    const int fr = lane & 15, kg = lane >> 4;

    const int bid = blockIdx.x;         // 0..2047
    const int kc  = bid & 63;           // k-chunk: cols [kc*128,+128); xcd=kc%8
    const int ig  = bid >> 6;           // i-group: rows [ig*256,+256)
    const int i0  = ig * 256 + w * 32;  // wave's 32-row strip

    // ---- stage the fragment slice (4096 uint4, coalesced)
    {
        const int kc4 = kc * 4;
        #pragma unroll
        for (int j = 0; j < 8; ++j) {
            const int idx   = j * 512 + t;     // 0..4095
            const int chunk = idx >> 6;        // dt*4 + k32
            const int off   = idx & 63;
            const int dt    = chunk >> 2, k32 = chunk & 3;
            *reinterpret_cast<uint4*>(&frg[chunk * 512 + off * 8]) =
                *reinterpret_cast<const uint4*>(
                    Asw2 + (size_t)(dt * 256 + kc4 + k32) * 512 + off * 8);
        }
    }
    __syncthreads();

    // lane's S rows: sub0 = i0+fr, sub1 = i0+16+fr; cols kc*128 + k*32 + kg*8
    const float* sg0 = S + (size_t)(i0 + fr) * BDIM + kc * 128 + kg * 8;
    const float* sg1 = sg0 + (size_t)16 * BDIM;

#define DECL_ACC(i) f32x4 a0_##i = {0.f,0.f,0.f,0.f}; f32x4 a1_##i = {0.f,0.f,0.f,0.f};
    REP16(DECL_ACC)
#undef DECL_ACC
    float s2 = 0.f;

    fv4 u0 = __builtin_nontemporal_load(reinterpret_cast<const fv4*>(sg0));
    fv4 v0 = __builtin_nontemporal_load(reinterpret_cast<const fv4*>(sg0 + 4));
    fv4 u1 = __builtin_nontemporal_load(reinterpret_cast<const fv4*>(sg1));
    fv4 v1 = __builtin_nontemporal_load(reinterpret_cast<const fv4*>(sg1 + 4));

    #pragma unroll 1
    for (int k = 0; k < 4; ++k) {
        fv4 nu0, nv0, nu1, nv1;
        if (k < 3) {
            const float* p0 = sg0 + (size_t)(k + 1) * 32;
            const float* p1 = sg1 + (size_t)(k + 1) * 32;
            nu0 = __builtin_nontemporal_load(reinterpret_cast<const fv4*>(p0));
            nv0 = __builtin_nontemporal_load(reinterpret_cast<const fv4*>(p0 + 4));
            nu1 = __builtin_nontemporal_load(reinterpret_cast<const fv4*>(p1));
            nv1 = __builtin_nontemporal_load(reinterpret_cast<const fv4*>(p1 + 4));
        }

        s16x8 af0, af1;
        af0[0] = (short)f2bf(u0.x); af0[1] = (short)f2bf(u0.y);
        af0[2] = (short)f2bf(u0.z); af0[3] = (short)f2bf(u0.w);
        af0[4] = (short)f2bf(v0.x); af0[5] = (short)f2bf(v0.y);
        af0[6] = (short)f2bf(v0.z); af0[7] = (short)f2bf(v0.w);
        af1[0] = (short)f2bf(u1.x); af1[1] = (short)f2bf(u1.y);
        af1[2] = (short)f2bf(u1.z); af1[3] = (short)f2bf(u1.w);
        af1[4] = (short)f2bf(v1.x); af1[5] = (short)f2bf(v1.y);
        af1[6] = (short)f2bf(v1.z); af1[7] = (short)f2bf(v1.w);
        s2 += u0.x*u0.x + u0.y*u0.y + u0.z*u0.z + u0.w*u0.w
            + v0.x*v0.x + v0.y*v0.y + v0.z*v0.z + v0.w*v0.w
            + u1.x*u1.x + u1.y*u1.y + u1.z*u1.z + u1.w*u1.w
            + v1.x*v1.x + v1.y*v1.y + v1.z*v1.z + v1.w*v1.w;

        const ushort* fb = frg + (size_t)k * 512 + lane * 8;
#define MF(i) { const s16x8 bf = *reinterpret_cast<const s16x8*>(fb + (i) * 2048);           \
                a0_##i = __builtin_amdgcn_mfma_f32_16x16x32_bf16(af0, bf, a0_##i, 0, 0, 0);  \
                a1_##i = __builtin_amdgcn_mfma_f32_16x16x32_bf16(af1, bf, a1_##i, 0, 0, 0); }
        REP16(MF)
#undef MF

        u0 = nu0; v0 = nv0; u1 = nu1; v1 = nv1;
    }

    // ---- epilogue (fully static): dot(acc, A_hat); col=fr -> d, row=kg*4+reg
    float dot = 0.f;
#define EP(i) { const int d = (i) * 16 + fr;                                              \
                const size_t ab = (size_t)(i0 >> 4) * 4096 + (size_t)(d >> 5) * 512       \
                                + (size_t)((d >> 3) & 3) * 128 + (size_t)(kg * 32) + (d & 7); \
                _Pragma("unroll")                                                         \
                for (int reg = 0; reg < 4; ++reg) {                                       \
                    const ushort uA = Asw[ab + reg * 8];                                  \
                    const ushort uB = Asw[ab + 4096 + reg * 8];                           \
                    dot += __uint_as_float((unsigned)uA << 16) * a0_##i[reg];             \
                    dot += __uint_as_float((unsigned)uB << 16) * a1_##i[reg];             \
                } }
    REP16(EP)
#undef EP

    #pragma unroll
    for (int off = 32; off > 0; off >>= 1) {
        dot += __shfl_down(dot, off);
        s2  += __shfl_down(s2, off);
    }
    if (lane == 0) {
        dotp[bid * 8 + w] = dot;
        s2p[bid * 8 + w]  = s2;
    }
}

// ---------------------------------------------------------------------------
// finalize: out = trip/B + (gram_ss - 2*dot + s2) / B^2
// ---------------------------------------------------------------------------
__global__ __launch_bounds__(256) void finalize(
    const float* __restrict__ pt, const float* __restrict__ dotp,
    const float* __restrict__ s2p, const float* __restrict__ gpart,
    float* __restrict__ out)
{
    __shared__ float sh[4];
    const int t = threadIdx.x;
    float trip = 0.f, sim = 0.f;
    for (int i = t; i < 2048; i += 256) trip += pt[i];
    for (int i = t; i < 16384; i += 256) sim += -2.f * dotp[i] + s2p[i];
    if (t < 64) sim += gpart[t];
    float v = trip * (1.0f / (float)BDIM)
            + sim  * (1.0f / ((float)BDIM * (float)BDIM));
    #pragma unroll
    for (int off = 32; off > 0; off >>= 1) v += __shfl_down(v, off);
    const int w = t >> 6, lane = t & 63;
    if (lane == 0) sh[w] = v;
    __syncthreads();
    if (t == 0) out[0] = sh[0] + sh[1] + sh[2] + sh[3];
}

extern "C" void kernel_launch(void* const* d_in, const int* in_sizes, int n_in,
                              void* d_out, int out_size, void* d_ws, size_t ws_size,
                              hipStream_t stream)
{
    const float* anchor   = (const float*)d_in[0];
    const float* positive = (const float*)d_in[1];
    const float* negative = (const float*)d_in[2];
    const float* S        = (const float*)d_in[3];
    float* out = (float*)d_out;

    float*  pt    = (float*)d_ws;                          // 2048 f
    float*  gpart = (float*)((char*)d_ws + 16384);         // 64 f
    float*  dotp  = (float*)((char*)d_ws + 65536);         // 16384 f
    float*  s2p   = (float*)((char*)d_ws + 131072);        // 16384 f
    ushort* Asw   = (ushort*)((char*)d_ws + (1u  << 20));  // 4 MB layout-1
    ushort* Asw2  = (ushort*)((char*)d_ws + (8u  << 20));  // 4 MB layout-2
    float*  Mpart = (float*)((char*)d_ws + (16u << 20));   // 8 MB gram partials

    row_stats<<<BDIM / 4, 256, 0, stream>>>(anchor, positive, negative, Asw, pt);
    transpose_ahat<<<64, 256, 0, stream>>>(Asw, Asw2);
    gram<<<dim3(32, 2), 256, 0, stream>>>(Asw2, Mpart);
    gram_reduce<<<64, 256, 0, stream>>>(Mpart, gpart);
    s_dot<<<2048, 512, 0, stream>>>(S, Asw, Asw2, dotp, s2p);
    finalize<<<1, 256, 0, stream>>>(pt, dotp, s2p, gpart, out);
}